// Round 7
// baseline (372.399 us; speedup 1.0000x reference)
//
#include <hip/hip_runtime.h>
#include <hip/hip_bf16.h>
#include <math.h>

#define DF 128           // feature dim (in and out)
#define TILE_EDGES 6144  // edges per tile in binc/binscatter -> 521 tiles
#define NPB 128          // nodes per bucket (bucket = col >> 7)
#define NB_MAX 1024      // max buckets (N <= 131072)
#define ADJ_MAX 5120     // per-bucket adjacency capacity (mean 4096, +16 sigma)
#define KP 136           // padded K stride (bf16) for W^T LDS tile in GEMM

typedef __hip_bfloat16 bf16;
typedef __hip_bfloat162 bf16x2;
typedef __attribute__((ext_vector_type(8))) short short8;
typedef __attribute__((ext_vector_type(4))) float f32x4;

__device__ inline short bf16bits(float f) {
    __hip_bfloat16 h = __float2bfloat16(f);
    return *reinterpret_cast<short*>(&h);
}

// ---------------- P1: per-tile LDS histogram -> global per-bucket totals ----------------
__global__ __launch_bounds__(512) void k_binc(const int* __restrict__ col,
                                              int* __restrict__ tot, int E, int NBk) {
    __shared__ int h[NB_MAX];
    int tid = threadIdx.x;
    for (int b = tid; b < NBk; b += 512) h[b] = 0;
    __syncthreads();
    int e0 = blockIdx.x * TILE_EDGES, e1 = min(e0 + TILE_EDGES, E);
    for (int e = e0 + tid; e < e1; e += 512)
        atomicAdd(&h[col[e] >> 7], 1);
    __syncthreads();
    for (int b = tid; b < NBk; b += 512)
        if (h[b]) atomicAdd(&tot[b], h[b]);
}

// ---------------- P2: single-block exclusive scan of per-bucket totals ----------------
__global__ __launch_bounds__(1024) void k_base(const int* __restrict__ tot,
                                               int* __restrict__ bucketBase,
                                               int* __restrict__ curg, int NBk, int E) {
    __shared__ int tmp[1024];
    int tid = threadIdx.x;
    int v = (tid < NBk) ? tot[tid] : 0;
    tmp[tid] = v;
    __syncthreads();
    for (int off = 1; off < 1024; off <<= 1) {
        int t = (tid >= off) ? tmp[tid - off] : 0;
        __syncthreads();
        tmp[tid] += t;
        __syncthreads();
    }
    if (tid < NBk) {
        int excl = tmp[tid] - v;
        bucketBase[tid] = excl;
        curg[tid] = excl;
    }
    if (tid == 0) bucketBase[NBk] = E;
}

// ---------------- P3: range-reserving bin scatter (LDS hist + 1 global atomic/bucket) --
// binned[pos] = (localNode << 24) | row   (row < 2^24, localNode < 128)
__global__ __launch_bounds__(512) void k_binscatter(const int* __restrict__ edge,
                                                    int* __restrict__ curg,
                                                    unsigned* __restrict__ binned,
                                                    int E, int NBk) {
    __shared__ int h[NB_MAX];
    __shared__ int cur[NB_MAX];
    int tid = threadIdx.x;
    for (int b = tid; b < NBk; b += 512) h[b] = 0;
    __syncthreads();
    int e0 = blockIdx.x * TILE_EDGES, e1 = min(e0 + TILE_EDGES, E);
    for (int e = e0 + tid; e < e1; e += 512)
        atomicAdd(&h[edge[E + e] >> 7], 1);
    __syncthreads();
    for (int b = tid; b < NBk; b += 512)
        cur[b] = h[b] ? atomicAdd(&curg[b], h[b]) : 0;   // reserve contiguous range
    __syncthreads();
    for (int e = e0 + tid; e < e1; e += 512) {
        int r = edge[e], c = edge[E + e];
        int pos = atomicAdd(&cur[c >> 7], 1);
        binned[pos] = ((unsigned)(c & (NPB - 1)) << 24) | (unsigned)r;
    }
}

// ---------------- P4: per-node degree -> dinv (needed by GEMM row pre-scale) ----------
__global__ __launch_bounds__(256) void k_dinv(const unsigned* __restrict__ binned,
                                              const int* __restrict__ bucketBase,
                                              float* __restrict__ dinvg, int N) {
    __shared__ int h[NPB];
    int tid = threadIdx.x;
    int b = blockIdx.x;
    int base = bucketBase[b];
    int cnt = bucketBase[b + 1] - base;
    if (tid < NPB) h[tid] = 0;
    __syncthreads();
    for (int i = tid; i < cnt; i += 256) atomicAdd(&h[binned[base + i] >> 24], 1);
    __syncthreads();
    if (tid < NPB) {
        int node = b * NPB + tid;
        if (node < N) dinvg[node] = rsqrtf((float)(h[tid] + 1));  // +1 self-loop
    }
}

// ---------------- P5: MFMA GEMM y = bf16((x @ W) * dinv[row]) (round-5 proven) --------
__global__ __launch_bounds__(256) void k_gemm(const float* __restrict__ x,
                                              const float* __restrict__ W,
                                              const float* __restrict__ dinv,
                                              bf16* __restrict__ y, int N) {
    __shared__ bf16 Wt[DF * KP];  // 34 KB
    int tid = threadIdx.x;
    for (int i = tid; i < DF * (DF / 4); i += 256) {
        int k = i >> 5;
        int n4 = (i & 31) * 4;
        float4 w = *(const float4*)(W + k * DF + n4);
        Wt[(n4 + 0) * KP + k] = __float2bfloat16(w.x);
        Wt[(n4 + 1) * KP + k] = __float2bfloat16(w.y);
        Wt[(n4 + 2) * KP + k] = __float2bfloat16(w.z);
        Wt[(n4 + 3) * KP + k] = __float2bfloat16(w.w);
    }
    __syncthreads();

    const int wv = tid >> 6, lane = tid & 63, m16 = lane & 15, q = lane >> 4;
    const int rbase = blockIdx.x * 64 + wv * 16;
    const int arow = min(rbase + m16, N - 1);

    f32x4 acc[8];
#pragma unroll
    for (int nt = 0; nt < 8; ++nt) acc[nt] = (f32x4){0.f, 0.f, 0.f, 0.f};

#pragma unroll
    for (int kc = 0; kc < 4; ++kc) {
        int k0 = kc * 32 + q * 8;
        float4 xa = *(const float4*)(x + (size_t)arow * DF + k0);
        float4 xb = *(const float4*)(x + (size_t)arow * DF + k0 + 4);
        short8 a;
        a[0] = bf16bits(xa.x); a[1] = bf16bits(xa.y);
        a[2] = bf16bits(xa.z); a[3] = bf16bits(xa.w);
        a[4] = bf16bits(xb.x); a[5] = bf16bits(xb.y);
        a[6] = bf16bits(xb.z); a[7] = bf16bits(xb.w);
#pragma unroll
        for (int nt = 0; nt < 8; ++nt) {
            short8 b = *(const short8*)(Wt + (nt * 16 + m16) * KP + k0);
            acc[nt] = __builtin_amdgcn_mfma_f32_16x16x32_bf16(a, b, acc[nt], 0, 0, 0);
        }
    }

#pragma unroll
    for (int r = 0; r < 4; ++r) {
        int orow = rbase + q * 4 + r;
        if (orow < N) {
            float dv = dinv[orow];
#pragma unroll
            for (int nt = 0; nt < 8; ++nt)
                y[(size_t)orow * DF + nt * 16 + m16] = __float2bfloat16(acc[nt][r] * dv);
        }
    }
}

// ---------------- P6: fused per-bucket sort (LDS) + gather + bias/ReLU ----------------
// Persistent blocks pull bucket ids from a global ticket for load balance.
__global__ __launch_bounds__(256) void k_gather(const bf16x2* __restrict__ y,  // 64/row
                                                const unsigned* __restrict__ binned,
                                                const int* __restrict__ bucketBase,
                                                const float* __restrict__ bias,
                                                int* __restrict__ ticket,
                                                float* __restrict__ out, int N, int NBk) {
    __shared__ int adj[ADJ_MAX];
    __shared__ int h[NPB], offs[NPB], cur[NPB];
    __shared__ int bshare;
    const int tid = threadIdx.x;
    const int wv = tid >> 6, lane = tid & 63;
    const float2 bb = *(const float2*)(bias + lane * 2);

    for (;;) {
        if (tid == 0) bshare = atomicAdd(ticket, 1);
        __syncthreads();
        int b = bshare;
        if (b >= NBk) break;

        int base = bucketBase[b];
        int cnt = min(bucketBase[b + 1] - base, ADJ_MAX);

        // counting sort into LDS
        if (tid < NPB) h[tid] = 0;
        __syncthreads();
        for (int i = tid; i < cnt; i += 256) atomicAdd(&h[binned[base + i] >> 24], 1);
        __syncthreads();
        if (tid < NPB) offs[tid] = h[tid];
        __syncthreads();
        for (int off = 1; off < NPB; off <<= 1) {
            int t = (tid >= off && tid < NPB) ? offs[tid - off] : 0;
            __syncthreads();
            if (tid < NPB) offs[tid] += t;
            __syncthreads();
        }
        if (tid < NPB) {
            offs[tid] -= h[tid];   // exclusive, bucket-local
            cur[tid] = offs[tid];
        }
        __syncthreads();
        for (int i = tid; i < cnt; i += 256) {
            unsigned v = binned[base + i];
            int p = atomicAdd(&cur[v >> 24], 1);
            adj[p] = (int)(v & 0xFFFFFFu);
        }
        __syncthreads();

        // gather: each wave handles nodes wv, wv+4, ...
        int nodesHere = min(NPB, N - b * NPB);
        for (int l = wv; l < nodesHere; l += 4) {
            int g = b * NPB + l;
            int d = h[l], start = offs[l];
            float2 acc = __bfloat1622float2(y[(size_t)g * 64 + lane]);  // self-loop
            int j = 0;
            for (; j + 8 <= d; j += 8) {
                int s0 = adj[start + j + 0];
                int s1 = adj[start + j + 1];
                int s2 = adj[start + j + 2];
                int s3 = adj[start + j + 3];
                int s4 = adj[start + j + 4];
                int s5 = adj[start + j + 5];
                int s6 = adj[start + j + 6];
                int s7 = adj[start + j + 7];
                float2 v0 = __bfloat1622float2(y[(size_t)s0 * 64 + lane]);
                float2 v1 = __bfloat1622float2(y[(size_t)s1 * 64 + lane]);
                float2 v2 = __bfloat1622float2(y[(size_t)s2 * 64 + lane]);
                float2 v3 = __bfloat1622float2(y[(size_t)s3 * 64 + lane]);
                float2 v4 = __bfloat1622float2(y[(size_t)s4 * 64 + lane]);
                float2 v5 = __bfloat1622float2(y[(size_t)s5 * 64 + lane]);
                float2 v6 = __bfloat1622float2(y[(size_t)s6 * 64 + lane]);
                float2 v7 = __bfloat1622float2(y[(size_t)s7 * 64 + lane]);
                acc.x += ((v0.x + v1.x) + (v2.x + v3.x)) + ((v4.x + v5.x) + (v6.x + v7.x));
                acc.y += ((v0.y + v1.y) + (v2.y + v3.y)) + ((v4.y + v5.y) + (v6.y + v7.y));
            }
            for (; j < d; ++j) {
                int s = adj[start + j];
                float2 v = __bfloat1622float2(y[(size_t)s * 64 + lane]);
                acc.x += v.x;
                acc.y += v.y;
            }
            float dv = rsqrtf((float)(d + 1));
            float2 o;
            o.x = fmaxf(fmaf(dv, acc.x, bb.x), 0.0f);
            o.y = fmaxf(fmaf(dv, acc.y, bb.y), 0.0f);
            *(float2*)(out + (size_t)g * DF + lane * 2) = o;
        }
        __syncthreads();   // protect adj/h/offs before next iteration
    }
}

extern "C" void kernel_launch(void* const* d_in, const int* in_sizes, int n_in,
                              void* d_out, int out_size, void* d_ws, size_t ws_size,
                              hipStream_t stream) {
    const float* x    = (const float*)d_in[0];
    const int*   edge = (const int*)d_in[1];   // [2, E] flat: rows then cols
    const float* W    = (const float*)d_in[2];
    const float* bias = (const float*)d_in[3];
    float*       out  = (float*)d_out;

    const int N = in_sizes[0] / DF;   // 100000
    const int E = in_sizes[1] / 2;    // 3200000

    const int NBk = (N + NPB - 1) / NPB;               // 782 buckets
    const int T   = (E + TILE_EDGES - 1) / TILE_EDGES; // 521 tiles

    // workspace layout (base 16B-aligned)
    bf16*     y          = (bf16*)d_ws;                  // N*128 bf16 (25.6 MB)
    float*    dinvg      = (float*)(y + (size_t)N * DF); // N f32
    int*      tot        = (int*)(dinvg + N);            // NBk
    int*      ticket     = tot + NBk;                    // 16 (pad)
    int*      bucketBase = ticket + 16;                  // NBk+16
    int*      curg       = bucketBase + NBk + 16;        // NBk
    unsigned* binned     = (unsigned*)(curg + NBk);      // E uints (12.8 MB)

    hipMemsetAsync(tot, 0, (size_t)(NBk + 16) * 4, stream);  // zeroes tot + ticket
    k_binc<<<T, 512, 0, stream>>>(edge + E, tot, E, NBk);
    k_base<<<1, 1024, 0, stream>>>(tot, bucketBase, curg, NBk, E);
    k_binscatter<<<T, 512, 0, stream>>>(edge, curg, binned, E, NBk);
    k_dinv<<<NBk, 256, 0, stream>>>(binned, bucketBase, dinvg, N);
    k_gemm<<<(N + 63) / 64, 256, 0, stream>>>(x, W, dinvg, y, N);
    k_gather<<<1024, 256, 0, stream>>>((const bf16x2*)y, binned, bucketBase, bias,
                                       ticket, out, N, NBk);
}

// Round 8
// 339.237 us; speedup vs baseline: 1.0978x; 1.0978x over previous
//
#include <hip/hip_runtime.h>
#include <hip/hip_bf16.h>
#include <math.h>

#define DF 128           // feature dim (in and out)
#define TILE_EDGES 6144  // edges per binscatter tile -> 521 tiles
#define NPB 256          // nodes per bucket (bucket = col >> 8)
#define NB_MAX 512       // max buckets (N <= 131072)
#define SLAB 9216        // per-bucket slab capacity (mean 8192, +11 sigma)

typedef __hip_bfloat16 bf16;
typedef __hip_bfloat162 bf16x2;
typedef __attribute__((ext_vector_type(8))) short short8;
typedef __attribute__((ext_vector_type(4))) float f32x4;

__device__ inline short bf16bits(float f) {
    __hip_bfloat16 h = __float2bfloat16(f);
    return *reinterpret_cast<short*>(&h);
}

// ---------------- P0: zero slab cursors + transpose W -> bf16 Wg[n][k] ----------------
__global__ __launch_bounds__(256) void k_init(const float* __restrict__ W,
                                              bf16* __restrict__ Wg,
                                              int* __restrict__ curg, int NBk) {
    int tid = threadIdx.x;
    for (int b = tid; b < NBk; b += 256) curg[b] = 0;
    for (int i = tid; i < DF * DF; i += 256) {
        int n = i & (DF - 1), k = i >> 7;
        Wg[n * DF + k] = __float2bfloat16(W[k * DF + n]);
    }
}

// ---------------- P1: slab bin-scatter (LDS hist + one global reserve per bucket) -----
// binned[b*SLAB + j] = (localNode << 24) | row   (localNode < 256, row < 2^24)
__global__ __launch_bounds__(512) void k_binscatter(const int* __restrict__ edge,
                                                    int* __restrict__ curg,
                                                    unsigned* __restrict__ binned,
                                                    int E, int NBk) {
    __shared__ int h[NB_MAX];
    __shared__ int cur[NB_MAX];
    int tid = threadIdx.x;
    for (int b = tid; b < NBk; b += 512) h[b] = 0;
    __syncthreads();
    int e0 = blockIdx.x * TILE_EDGES, e1 = min(e0 + TILE_EDGES, E);
    for (int e = e0 + tid; e < e1; e += 512)
        atomicAdd(&h[edge[E + e] >> 8], 1);
    __syncthreads();
    for (int b = tid; b < NBk; b += 512)
        cur[b] = h[b] ? b * SLAB + atomicAdd(&curg[b], h[b]) : 0;  // reserve range in slab
    __syncthreads();
    for (int e = e0 + tid; e < e1; e += 512) {
        int r = edge[e], c = edge[E + e];
        int b = c >> 8;
        int pos = atomicAdd(&cur[b], 1);
        if (pos < (b + 1) * SLAB)   // overflow guard (P ~ 1e-26)
            binned[pos] = ((unsigned)(c & (NPB - 1)) << 24) | (unsigned)r;
    }
}

// ---------------- P2: per-bucket counting sort -> slab CSR; emits offsets/deg/dinv ----
__global__ __launch_bounds__(512) void k_bucket(const unsigned* __restrict__ binned,
                                                const int* __restrict__ curg,
                                                int* __restrict__ ssrc,
                                                int* __restrict__ offsets,
                                                int* __restrict__ deg,
                                                float* __restrict__ dinv, int N) {
    __shared__ int h[NPB], sc[NPB], cur[NPB];
    int tid = threadIdx.x;
    int b = blockIdx.x;
    int base = b * SLAB;
    int cnt = min(curg[b], SLAB);
    if (tid < NPB) h[tid] = 0;
    __syncthreads();
    for (int i = tid; i < cnt; i += 512)
        atomicAdd(&h[binned[base + i] >> 24], 1);
    __syncthreads();
    if (tid < NPB) sc[tid] = h[tid];
    __syncthreads();
    for (int off = 1; off < NPB; off <<= 1) {
        int tv = (tid >= off && tid < NPB) ? sc[tid - off] : 0;
        __syncthreads();
        if (tid < NPB) sc[tid] += tv;
        __syncthreads();
    }
    if (tid < NPB) {
        int excl = sc[tid] - h[tid];
        cur[tid] = base + excl;
        int node = b * NPB + tid;
        if (node < N) {
            offsets[node] = base + excl;
            deg[node] = h[tid];
            dinv[node] = rsqrtf((float)(h[tid] + 1));  // +1 self-loop
        }
    }
    __syncthreads();
    for (int i = tid; i < cnt; i += 512) {
        unsigned v = binned[base + i];
        int pos = atomicAdd(&cur[v >> 24], 1);
        ssrc[pos] = (int)(v & 0xFFFFFFu);
    }
}

// ---------------- P3: MFMA GEMM y = bf16((x @ W) * dinv[row]), W frags from global ----
// 16x16x32 bf16. A: A[m=lane&15][k=quad*8+j]; B: B[k=quad*8+j][n=lane&15];
// C/D: col=lane&15, row=quad*4+reg (m89-verified). Wg is 32 KB -> L1/L2-resident.
__global__ __launch_bounds__(256) void k_gemm(const float* __restrict__ x,
                                              const bf16* __restrict__ Wg,
                                              const float* __restrict__ dinv,
                                              bf16* __restrict__ y, int N) {
    const int tid = threadIdx.x;
    const int wv = tid >> 6, lane = tid & 63, m16 = lane & 15, q = lane >> 4;
    const int rbase = blockIdx.x * 64 + wv * 16;
    const int arow = min(rbase + m16, N - 1);

    f32x4 acc[8];
#pragma unroll
    for (int nt = 0; nt < 8; ++nt) acc[nt] = (f32x4){0.f, 0.f, 0.f, 0.f};

#pragma unroll
    for (int kc = 0; kc < 4; ++kc) {
        int k0 = kc * 32 + q * 8;
        float4 xa = *(const float4*)(x + (size_t)arow * DF + k0);
        float4 xb = *(const float4*)(x + (size_t)arow * DF + k0 + 4);
        short8 a;
        a[0] = bf16bits(xa.x); a[1] = bf16bits(xa.y);
        a[2] = bf16bits(xa.z); a[3] = bf16bits(xa.w);
        a[4] = bf16bits(xb.x); a[5] = bf16bits(xb.y);
        a[6] = bf16bits(xb.z); a[7] = bf16bits(xb.w);
#pragma unroll
        for (int nt = 0; nt < 8; ++nt) {
            short8 b = *(const short8*)(Wg + (nt * 16 + m16) * DF + k0);
            acc[nt] = __builtin_amdgcn_mfma_f32_16x16x32_bf16(a, b, acc[nt], 0, 0, 0);
        }
    }

#pragma unroll
    for (int r = 0; r < 4; ++r) {
        int orow = rbase + q * 4 + r;
        if (orow < N) {
            float dv = dinv[orow];
#pragma unroll
            for (int nt = 0; nt < 8; ++nt)
                y[(size_t)orow * DF + nt * 16 + m16] = __float2bfloat16(acc[nt][r] * dv);
        }
    }
}

// ---------------- P4: gather-aggregate, one wave per target node (r4-proven) ----------
__global__ __launch_bounds__(256) void k_gather(const bf16x2* __restrict__ y,  // 64/row
                                                const int* __restrict__ ssrc,
                                                const int* __restrict__ offsets,
                                                const int* __restrict__ deg,
                                                const float* __restrict__ dinv,
                                                const float* __restrict__ b,
                                                float* __restrict__ out, int N) {
    int wave = (blockIdx.x * 256 + threadIdx.x) >> 6;  // 4 waves/block = 4 nodes
    int lane = threadIdx.x & 63;
    if (wave >= N) return;
    int c = wave;
    int start = offsets[c];
    int d = deg[c];

    float2 acc = __bfloat1622float2(y[(size_t)c * 64 + lane]);  // self-loop term

    for (int base = 0; base < d; base += 64) {
        int nb = min(64, d - base);                       // nb >= 1 here
        int idx = ssrc[start + base + min(lane, nb - 1)]; // coalesced, clamped
        int j = 0;
        for (; j + 8 <= nb; j += 8) {
            int r0 = __shfl(idx, j + 0);
            int r1 = __shfl(idx, j + 1);
            int r2 = __shfl(idx, j + 2);
            int r3 = __shfl(idx, j + 3);
            int r4 = __shfl(idx, j + 4);
            int r5 = __shfl(idx, j + 5);
            int r6 = __shfl(idx, j + 6);
            int r7 = __shfl(idx, j + 7);
            float2 v0 = __bfloat1622float2(y[(size_t)r0 * 64 + lane]);
            float2 v1 = __bfloat1622float2(y[(size_t)r1 * 64 + lane]);
            float2 v2 = __bfloat1622float2(y[(size_t)r2 * 64 + lane]);
            float2 v3 = __bfloat1622float2(y[(size_t)r3 * 64 + lane]);
            float2 v4 = __bfloat1622float2(y[(size_t)r4 * 64 + lane]);
            float2 v5 = __bfloat1622float2(y[(size_t)r5 * 64 + lane]);
            float2 v6 = __bfloat1622float2(y[(size_t)r6 * 64 + lane]);
            float2 v7 = __bfloat1622float2(y[(size_t)r7 * 64 + lane]);
            acc.x += ((v0.x + v1.x) + (v2.x + v3.x)) + ((v4.x + v5.x) + (v6.x + v7.x));
            acc.y += ((v0.y + v1.y) + (v2.y + v3.y)) + ((v4.y + v5.y) + (v6.y + v7.y));
        }
        for (; j < nb; ++j) {
            int r = __shfl(idx, j);
            float2 v = __bfloat1622float2(y[(size_t)r * 64 + lane]);
            acc.x += v.x;
            acc.y += v.y;
        }
    }

    float dv = dinv[c];
    float2 bb = *(const float2*)(b + lane * 2);
    float2 o;
    o.x = fmaxf(fmaf(dv, acc.x, bb.x), 0.0f);
    o.y = fmaxf(fmaf(dv, acc.y, bb.y), 0.0f);
    *(float2*)(out + (size_t)c * DF + lane * 2) = o;
}

extern "C" void kernel_launch(void* const* d_in, const int* in_sizes, int n_in,
                              void* d_out, int out_size, void* d_ws, size_t ws_size,
                              hipStream_t stream) {
    const float* x    = (const float*)d_in[0];
    const int*   edge = (const int*)d_in[1];   // [2, E] flat: rows then cols
    const float* W    = (const float*)d_in[2];
    const float* bias = (const float*)d_in[3];
    float*       out  = (float*)d_out;

    const int N = in_sizes[0] / DF;   // 100000
    const int E = in_sizes[1] / 2;    // 3200000

    const int NBk = (N + NPB - 1) / NPB;               // 391 buckets
    const int T   = (E + TILE_EDGES - 1) / TILE_EDGES; // 521 tiles

    // workspace layout (base 16B-aligned; ~58 MB total)
    bf16*     y       = (bf16*)d_ws;                   // N*128 bf16 (25.6 MB)
    float*    dinvg   = (float*)(y + (size_t)N * DF);  // N f32
    int*      deg     = (int*)(dinvg + N);             // N
    int*      offsets = deg + N;                       // N
    int*      curg    = offsets + N;                   // NBk (+pad 16)
    bf16*     Wg      = (bf16*)(curg + NBk + 16);      // 128*128 bf16 (32 KB)
    unsigned* binned  = (unsigned*)(Wg + DF * DF);     // NBk*SLAB uints (14.4 MB)
    int*      ssrc    = (int*)(binned + (size_t)NBk * SLAB);  // NBk*SLAB ints (14.4 MB)

    k_init<<<1, 256, 0, stream>>>(W, Wg, curg, NBk);
    k_binscatter<<<T, 512, 0, stream>>>(edge, curg, binned, E, NBk);
    k_bucket<<<NBk, 512, 0, stream>>>(binned, curg, ssrc, offsets, deg, dinvg, N);
    k_gemm<<<(N + 63) / 64, 256, 0, stream>>>(x, Wg, dinvg, y, N);
    k_gather<<<(N + 3) / 4, 256, 0, stream>>>((const bf16x2*)y, ssrc, offsets, deg,
                                              dinvg, bias, out, N);
}

// Round 9
// 327.662 us; speedup vs baseline: 1.1365x; 1.0353x over previous
//
#include <hip/hip_runtime.h>
#include <hip/hip_bf16.h>
#include <math.h>

#define DF 128            // feature dim (in and out)
#define TILE_EDGES 12288  // edges per binscatter tile -> 261 tiles (~32-edge runs/bucket)
#define NPB 256           // nodes per bucket (bucket = col >> 8)
#define NB_MAX 512        // max buckets (N <= 131072)
#define SLAB 9216         // per-bucket slab capacity (mean 8192, +11 sigma)
#define KP 136            // padded K stride (bf16) for W^T LDS tile in GEMM

typedef __hip_bfloat16 bf16;
typedef __hip_bfloat162 bf16x2;
typedef __attribute__((ext_vector_type(8))) short short8;
typedef __attribute__((ext_vector_type(4))) float f32x4;

__device__ inline short bf16bits(float f) {
    __hip_bfloat16 h = __float2bfloat16(f);
    return *reinterpret_cast<short*>(&h);
}

// ---------------- P0: zero slab cursors + transpose W -> bf16 Wg[n][k] ----------------
__global__ __launch_bounds__(256) void k_init(const float* __restrict__ W,
                                              bf16* __restrict__ Wg,
                                              int* __restrict__ curg, int NBk) {
    int tid = threadIdx.x;
    for (int b = tid; b < NBk; b += 256) curg[b] = 0;
    for (int i = tid; i < DF * DF; i += 256) {
        int n = i & (DF - 1), k = i >> 7;
        Wg[n * DF + k] = __float2bfloat16(W[k * DF + n]);
    }
}

// ---------------- P1: slab bin-scatter (LDS hist + one global reserve per bucket) -----
// binned[b*SLAB + j] = (localNode << 24) | row   (localNode < 256, row < 2^24)
__global__ __launch_bounds__(512) void k_binscatter(const int* __restrict__ edge,
                                                    int* __restrict__ curg,
                                                    unsigned* __restrict__ binned,
                                                    int E, int NBk) {
    __shared__ int h[NB_MAX];
    __shared__ int cur[NB_MAX];
    int tid = threadIdx.x;
    for (int b = tid; b < NBk; b += 512) h[b] = 0;
    __syncthreads();
    int e0 = blockIdx.x * TILE_EDGES, e1 = min(e0 + TILE_EDGES, E);
    for (int e = e0 + tid; e < e1; e += 512)
        atomicAdd(&h[edge[E + e] >> 8], 1);
    __syncthreads();
    for (int b = tid; b < NBk; b += 512)
        cur[b] = h[b] ? b * SLAB + atomicAdd(&curg[b], h[b]) : 0;  // reserve range in slab
    __syncthreads();
    for (int e = e0 + tid; e < e1; e += 512) {
        int r = edge[e], c = edge[E + e];
        int b = c >> 8;
        int pos = atomicAdd(&cur[b], 1);
        if (pos < (b + 1) * SLAB)   // overflow guard (P ~ 1e-26)
            binned[pos] = ((unsigned)(c & (NPB - 1)) << 24) | (unsigned)r;
    }
}

// ---------------- P2: per-bucket counting sort -> slab CSR; emits offsets/deg/dinv ----
__global__ __launch_bounds__(512) void k_bucket(const unsigned* __restrict__ binned,
                                                const int* __restrict__ curg,
                                                int* __restrict__ ssrc,
                                                int* __restrict__ offsets,
                                                int* __restrict__ deg,
                                                float* __restrict__ dinv, int N) {
    __shared__ int h[NPB], sc[NPB], cur[NPB];
    int tid = threadIdx.x;
    int b = blockIdx.x;
    int base = b * SLAB;
    int cnt = min(curg[b], SLAB);
    if (tid < NPB) h[tid] = 0;
    __syncthreads();
    for (int i = tid; i < cnt; i += 512)
        atomicAdd(&h[binned[base + i] >> 24], 1);
    __syncthreads();
    if (tid < NPB) sc[tid] = h[tid];
    __syncthreads();
    for (int off = 1; off < NPB; off <<= 1) {
        int tv = (tid >= off && tid < NPB) ? sc[tid - off] : 0;
        __syncthreads();
        if (tid < NPB) sc[tid] += tv;
        __syncthreads();
    }
    if (tid < NPB) {
        int excl = sc[tid] - h[tid];
        cur[tid] = base + excl;
        int node = b * NPB + tid;
        if (node < N) {
            offsets[node] = base + excl;
            deg[node] = h[tid];
            dinv[node] = rsqrtf((float)(h[tid] + 1));  // +1 self-loop
        }
    }
    __syncthreads();
    for (int i = tid; i < cnt; i += 512) {
        unsigned v = binned[base + i];
        int pos = atomicAdd(&cur[v >> 24], 1);
        ssrc[pos] = (int)(v & 0xFFFFFFu);
    }
}

// ---------------- P3: MFMA GEMM y = bf16((x @ W) * dinv[row]) ----------------
// 16x16x32 bf16. A: A[m=lane&15][k=quad*8+j]; B: B[k=quad*8+j][n=lane&15];
// C/D: col=lane&15, row=quad*4+reg (m89-verified).
// W^T staged in LDS from pre-transposed bf16 Wg via short8 copies (KP=136 pad:
// rows 0-7 fill all 32 banks for b128 reads, rows 8-15 alias 2-way = free).
__global__ __launch_bounds__(256) void k_gemm(const float* __restrict__ x,
                                              const bf16* __restrict__ Wg,
                                              const float* __restrict__ dinv,
                                              bf16* __restrict__ y, int N) {
    __shared__ bf16 Wt[DF * KP];  // 34 KB
    const int tid = threadIdx.x;
    for (int i = tid; i < DF * (DF / 8); i += 256) {   // 2048 short8 chunks
        int n = i >> 4;          // row 0..127
        int c8 = (i & 15) * 8;   // col 0..120 step 8
        *(short8*)(Wt + n * KP + c8) = *(const short8*)(Wg + n * DF + c8);
    }
    __syncthreads();

    const int wv = tid >> 6, lane = tid & 63, m16 = lane & 15, q = lane >> 4;
    const int rbase = blockIdx.x * 64 + wv * 16;
    const int arow = min(rbase + m16, N - 1);

    f32x4 acc[8];
#pragma unroll
    for (int nt = 0; nt < 8; ++nt) acc[nt] = (f32x4){0.f, 0.f, 0.f, 0.f};

#pragma unroll
    for (int kc = 0; kc < 4; ++kc) {
        int k0 = kc * 32 + q * 8;
        float4 xa = *(const float4*)(x + (size_t)arow * DF + k0);
        float4 xb = *(const float4*)(x + (size_t)arow * DF + k0 + 4);
        short8 a;
        a[0] = bf16bits(xa.x); a[1] = bf16bits(xa.y);
        a[2] = bf16bits(xa.z); a[3] = bf16bits(xa.w);
        a[4] = bf16bits(xb.x); a[5] = bf16bits(xb.y);
        a[6] = bf16bits(xb.z); a[7] = bf16bits(xb.w);
#pragma unroll
        for (int nt = 0; nt < 8; ++nt) {
            short8 b = *(const short8*)(Wt + (nt * 16 + m16) * KP + k0);
            acc[nt] = __builtin_amdgcn_mfma_f32_16x16x32_bf16(a, b, acc[nt], 0, 0, 0);
        }
    }

#pragma unroll
    for (int r = 0; r < 4; ++r) {
        int orow = rbase + q * 4 + r;
        if (orow < N) {
            float dv = dinv[orow];
#pragma unroll
            for (int nt = 0; nt < 8; ++nt)
                y[(size_t)orow * DF + nt * 16 + m16] = __float2bfloat16(acc[nt][r] * dv);
        }
    }
}

// ---------------- P4: gather-aggregate, one wave per target node (r4-proven) ----------
__global__ __launch_bounds__(256) void k_gather(const bf16x2* __restrict__ y,  // 64/row
                                                const int* __restrict__ ssrc,
                                                const int* __restrict__ offsets,
                                                const int* __restrict__ deg,
                                                const float* __restrict__ dinv,
                                                const float* __restrict__ b,
                                                float* __restrict__ out, int N) {
    int wave = (blockIdx.x * 256 + threadIdx.x) >> 6;  // 4 waves/block = 4 nodes
    int lane = threadIdx.x & 63;
    if (wave >= N) return;
    int c = wave;
    int start = offsets[c];
    int d = deg[c];

    float2 acc = __bfloat1622float2(y[(size_t)c * 64 + lane]);  // self-loop term

    for (int base = 0; base < d; base += 64) {
        int nb = min(64, d - base);                       // nb >= 1 here
        int idx = ssrc[start + base + min(lane, nb - 1)]; // coalesced, clamped
        int j = 0;
        for (; j + 8 <= nb; j += 8) {
            int r0 = __shfl(idx, j + 0);
            int r1 = __shfl(idx, j + 1);
            int r2 = __shfl(idx, j + 2);
            int r3 = __shfl(idx, j + 3);
            int r4 = __shfl(idx, j + 4);
            int r5 = __shfl(idx, j + 5);
            int r6 = __shfl(idx, j + 6);
            int r7 = __shfl(idx, j + 7);
            float2 v0 = __bfloat1622float2(y[(size_t)r0 * 64 + lane]);
            float2 v1 = __bfloat1622float2(y[(size_t)r1 * 64 + lane]);
            float2 v2 = __bfloat1622float2(y[(size_t)r2 * 64 + lane]);
            float2 v3 = __bfloat1622float2(y[(size_t)r3 * 64 + lane]);
            float2 v4 = __bfloat1622float2(y[(size_t)r4 * 64 + lane]);
            float2 v5 = __bfloat1622float2(y[(size_t)r5 * 64 + lane]);
            float2 v6 = __bfloat1622float2(y[(size_t)r6 * 64 + lane]);
            float2 v7 = __bfloat1622float2(y[(size_t)r7 * 64 + lane]);
            acc.x += ((v0.x + v1.x) + (v2.x + v3.x)) + ((v4.x + v5.x) + (v6.x + v7.x));
            acc.y += ((v0.y + v1.y) + (v2.y + v3.y)) + ((v4.y + v5.y) + (v6.y + v7.y));
        }
        for (; j < nb; ++j) {
            int r = __shfl(idx, j);
            float2 v = __bfloat1622float2(y[(size_t)r * 64 + lane]);
            acc.x += v.x;
            acc.y += v.y;
        }
    }

    float dv = dinv[c];
    float2 bb = *(const float2*)(b + lane * 2);
    float2 o;
    o.x = fmaxf(fmaf(dv, acc.x, bb.x), 0.0f);
    o.y = fmaxf(fmaf(dv, acc.y, bb.y), 0.0f);
    *(float2*)(out + (size_t)c * DF + lane * 2) = o;
}

extern "C" void kernel_launch(void* const* d_in, const int* in_sizes, int n_in,
                              void* d_out, int out_size, void* d_ws, size_t ws_size,
                              hipStream_t stream) {
    const float* x    = (const float*)d_in[0];
    const int*   edge = (const int*)d_in[1];   // [2, E] flat: rows then cols
    const float* W    = (const float*)d_in[2];
    const float* bias = (const float*)d_in[3];
    float*       out  = (float*)d_out;

    const int N = in_sizes[0] / DF;   // 100000
    const int E = in_sizes[1] / 2;    // 3200000

    const int NBk = (N + NPB - 1) / NPB;               // 391 buckets
    const int T   = (E + TILE_EDGES - 1) / TILE_EDGES; // 261 tiles

    // workspace layout (base 16B-aligned; ~58 MB total)
    bf16*     y       = (bf16*)d_ws;                   // N*128 bf16 (25.6 MB)
    float*    dinvg   = (float*)(y + (size_t)N * DF);  // N f32
    int*      deg     = (int*)(dinvg + N);             // N
    int*      offsets = deg + N;                       // N
    int*      curg    = offsets + N;                   // NBk (+pad 16)
    bf16*     Wg      = (bf16*)(curg + NBk + 16);      // 128*128 bf16 (32 KB)
    unsigned* binned  = (unsigned*)(Wg + DF * DF);     // NBk*SLAB uints (14.4 MB)
    int*      ssrc    = (int*)(binned + (size_t)NBk * SLAB);  // NBk*SLAB ints (14.4 MB)

    k_init<<<1, 256, 0, stream>>>(W, Wg, curg, NBk);
    k_binscatter<<<T, 512, 0, stream>>>(edge, curg, binned, E, NBk);
    k_bucket<<<NBk, 512, 0, stream>>>(binned, curg, ssrc, offsets, deg, dinvg, N);
    k_gemm<<<(N + 63) / 64, 256, 0, stream>>>(x, Wg, dinvg, y, N);
    k_gather<<<(N + 3) / 4, 256, 0, stream>>>((const bf16x2*)y, ssrc, offsets, deg,
                                              dinvg, bias, out, N);
}